// Round 2
// baseline (1922.396 us; speedup 1.0000x reference)
//
#include <hip/hip_runtime.h>
#include <hip/hip_bf16.h>
#include <cmath>

// SeqAttention: B=16, S=2048, D=1024, E2=4096.
// bf16 MFMA (16x16x32) for all four GEMMs; fp32 accum + fp32 LN/softmax math.
// Workspace: 208 MiB (see carve-up below). d_out doubles as fp32 scratch
// (x_pre, then y), finished in-place by LN2.

typedef __bf16 bf16;
typedef __attribute__((ext_vector_type(8))) __bf16 bf16x8;
typedef __attribute__((ext_vector_type(4))) __bf16 bf16x4;
typedef __attribute__((ext_vector_type(4))) float f32x4;

static constexpr int kB  = 16;
static constexpr int kS  = 2048;
static constexpr int kD  = 1024;
static constexpr int kE2 = 4096;
static constexpr int kCB = 4;      // batches per attention chunk
static constexpr int kFR = 8192;   // rows per FFN chunk

// ---------------- fp32 -> bf16 elementwise (4 elems/thread) ----------------
__global__ __launch_bounds__(256) void cvt_bf16_kernel(const float* __restrict__ in,
                                                       bf16* __restrict__ out) {
    size_t i = ((size_t)blockIdx.x * 256 + threadIdx.x) * 4;
    float4 v = *(const float4*)(in + i);
    bf16x4 o;
    o.x = (bf16)v.x; o.y = (bf16)v.y; o.z = (bf16)v.z; o.w = (bf16)v.w;
    *(bf16x4*)(out + i) = o;
}

// ---------------- tiled transpose + convert: out[c][r] = bf16(in[r][c]) ----
__global__ void transpose_cvt_kernel(const float* __restrict__ in, bf16* __restrict__ out,
                                     int R, int C, long long sIn, long long sOut) {
    __shared__ float tile[32][33];
    in  += (size_t)blockIdx.z * sIn;
    out += (size_t)blockIdx.z * sOut;
    const int c0 = blockIdx.x * 32, r0 = blockIdx.y * 32;
    const int tx = threadIdx.x, ty = threadIdx.y;
#pragma unroll
    for (int k = 0; k < 32; k += 8)
        tile[ty + k][tx] = in[(size_t)(r0 + ty + k) * C + (c0 + tx)];
    __syncthreads();
#pragma unroll
    for (int k = 0; k < 32; k += 8)
        out[(size_t)(c0 + ty + k) * R + (r0 + tx)] = (bf16)tile[tx][ty + k];
}

// ---------------- GEMM: C(MxN) = A(MxK) . B^T, B given as (NxK) -----------
// Both operands bf16, K-contiguous. 128x128 block tile, BK=32, 4 waves 2x2,
// each wave 64x64 via 4x4 grid of 16x16x32 MFMAs (m93-verified structure).
// MODE 0: Cb = bf16(acc*scale)                (attention scores, bf16)
// MODE 1: C  = acc + resF                     (attn_out + residual, fp32)
// MODE 2: Cb = bf16(gelu_exact(acc + bias))   (FFN1 -> h)
// MODE 3: C  = acc + bias + resB              (FFN2 + residual, fp32)
template <int MODE>
__global__ __launch_bounds__(256)
void gemm_bt_kernel(const bf16* __restrict__ A, const bf16* __restrict__ Bm,
                    float* __restrict__ C, bf16* __restrict__ Cb,
                    const float* __restrict__ bias,
                    const float* __restrict__ resF, const bf16* __restrict__ resB,
                    int N, int K,
                    long long sA, long long sB, long long sC, long long sRes,
                    float scale) {
    __shared__ __align__(16) bf16 As[128 * 32];
    __shared__ __align__(16) bf16 Bs[128 * 32];
    const int tid  = threadIdx.x;
    const int lane = tid & 63;
    const int wv   = tid >> 6;
    const int wm = wv >> 1, wn = wv & 1;
    const int quad = lane >> 4, l15 = lane & 15;
    const long long z = blockIdx.z;
    const bf16* Ab = A  + z * sA + (size_t)blockIdx.y * 128 * K;
    const bf16* Bb = Bm + z * sB + (size_t)blockIdx.x * 128 * K;
    const int r0c = tid >> 2;          // 0..63 (staging row)
    const int c0c = (tid & 3) * 8;     // staging col (bf16 elems)

    f32x4 acc[4][4];
#pragma unroll
    for (int i = 0; i < 4; i++)
#pragma unroll
        for (int j = 0; j < 4; j++) {
            f32x4 zv = {0.0f, 0.0f, 0.0f, 0.0f};
            acc[i][j] = zv;
        }

    for (int k0 = 0; k0 < K; k0 += 32) {
        uint4 a0 = *(const uint4*)(Ab + (size_t)r0c * K + k0 + c0c);
        uint4 a1 = *(const uint4*)(Ab + (size_t)(r0c + 64) * K + k0 + c0c);
        uint4 b0 = *(const uint4*)(Bb + (size_t)r0c * K + k0 + c0c);
        uint4 b1 = *(const uint4*)(Bb + (size_t)(r0c + 64) * K + k0 + c0c);
        __syncthreads();   // previous iteration's LDS reads complete
        *(uint4*)&As[(size_t)tid * 8]         = a0;
        *(uint4*)&As[(size_t)(tid + 256) * 8] = a1;
        *(uint4*)&Bs[(size_t)tid * 8]         = b0;
        *(uint4*)&Bs[(size_t)(tid + 256) * 8] = b1;
        __syncthreads();
        bf16x8 af[4], bfr[4];
#pragma unroll
        for (int i = 0; i < 4; i++)   // A frag: m = l15 (+tile), k = quad*8+j
            af[i] = *(const bf16x8*)&As[(wm * 64 + i * 16 + l15) * 32 + quad * 8];
#pragma unroll
        for (int j = 0; j < 4; j++)   // B frag: n = l15 (+tile), k = quad*8+j
            bfr[j] = *(const bf16x8*)&Bs[(wn * 64 + j * 16 + l15) * 32 + quad * 8];
#pragma unroll
        for (int i = 0; i < 4; i++)
#pragma unroll
            for (int j = 0; j < 4; j++)
                acc[i][j] = __builtin_amdgcn_mfma_f32_16x16x32_bf16(af[i], bfr[j], acc[i][j], 0, 0, 0);
    }

    // epilogue: C/D layout col = l15, row = quad*4 + reg (m89-verified)
    const size_t m0 = (size_t)blockIdx.y * 128 + wm * 64;
    const size_t n0 = (size_t)blockIdx.x * 128 + wn * 64;
#pragma unroll
    for (int i = 0; i < 4; i++) {
#pragma unroll
        for (int j = 0; j < 4; j++) {
            const size_t col = n0 + j * 16 + l15;
            const float bcol = (MODE == 2 || MODE == 3) ? bias[col] : 0.0f;
#pragma unroll
            for (int rr = 0; rr < 4; rr++) {
                const size_t row = m0 + i * 16 + quad * 4 + rr;
                const float v = acc[i][j][rr];
                if (MODE == 0) {
                    Cb[z * sC + row * N + col] = (bf16)(v * scale);
                } else if (MODE == 1) {
                    C[z * sC + row * N + col] = v + resF[z * sRes + row * N + col];
                } else if (MODE == 2) {
                    const float t = v + bcol;
                    const float gl = 0.5f * t * (1.0f + erff(t * 0.70710678118654752f));
                    Cb[row * N + col] = (bf16)gl;
                } else {
                    C[row * N + col] = v + bcol + (float)resB[row * N + col];
                }
            }
        }
    }
}

// ---------------- row softmax over T=2048, bf16 in-place -------------------
__global__ __launch_bounds__(256)
void softmax_bf16_kernel(bf16* __restrict__ SP) {
    __shared__ float red[8];
    const size_t row = blockIdx.x;
    bf16* p = SP + row * kS;
    const int tid = threadIdx.x;
    bf16x8 v = *(const bf16x8*)(p + tid * 8);
    float f[8];
#pragma unroll
    for (int i = 0; i < 8; i++) f[i] = (float)v[i];
    float m = f[0];
#pragma unroll
    for (int i = 1; i < 8; i++) m = fmaxf(m, f[i]);
#pragma unroll
    for (int o = 32; o > 0; o >>= 1) m = fmaxf(m, __shfl_down(m, o, 64));
    if ((tid & 63) == 0) red[tid >> 6] = m;
    __syncthreads();
    m = fmaxf(fmaxf(red[0], red[1]), fmaxf(red[2], red[3]));
    float e[8], s = 0.0f;
#pragma unroll
    for (int i = 0; i < 8; i++) { e[i] = __expf(f[i] - m); s += e[i]; }
#pragma unroll
    for (int o = 32; o > 0; o >>= 1) s += __shfl_down(s, o, 64);
    __syncthreads();
    if ((tid & 63) == 0) red[4 + (tid >> 6)] = s;
    __syncthreads();
    s = red[4] + red[5] + red[6] + red[7];
    const float inv = 1.0f / s;
    bf16x8 o;
#pragma unroll
    for (int i = 0; i < 8; i++) o[i] = (bf16)(e[i] * inv);
    *(bf16x8*)(p + tid * 8) = o;
}

// ---------------- row LayerNorm over D=1024 (fp32 in), fp32/bf16 out -------
__global__ __launch_bounds__(256)
void layernorm_kernel(const float* __restrict__ in, const float* __restrict__ g,
                      const float* __restrict__ be, float* __restrict__ outF,
                      bf16* __restrict__ outB) {
    __shared__ float red[8];
    const size_t row = blockIdx.x;
    const float* src = in + row * kD;
    const int tid = threadIdx.x;
    float4 v = *(const float4*)(src + tid * 4);
    float s = v.x + v.y + v.z + v.w;
#pragma unroll
    for (int o = 32; o > 0; o >>= 1) s += __shfl_down(s, o, 64);
    if ((tid & 63) == 0) red[tid >> 6] = s;
    __syncthreads();
    const float mu = (red[0] + red[1] + red[2] + red[3]) * (1.0f / kD);
    const float d0 = v.x - mu, d1 = v.y - mu, d2 = v.z - mu, d3 = v.w - mu;
    float ss = d0 * d0 + d1 * d1 + d2 * d2 + d3 * d3;
#pragma unroll
    for (int o = 32; o > 0; o >>= 1) ss += __shfl_down(ss, o, 64);
    __syncthreads();
    if ((tid & 63) == 0) red[4 + (tid >> 6)] = ss;
    __syncthreads();
    const float var = (red[4] + red[5] + red[6] + red[7]) * (1.0f / kD);
    const float rstd = rsqrtf(var + 1e-5f);
    float4 gg = *(const float4*)(g + tid * 4);
    float4 bb = *(const float4*)(be + tid * 4);
    float4 o;
    o.x = d0 * rstd * gg.x + bb.x;
    o.y = d1 * rstd * gg.y + bb.y;
    o.z = d2 * rstd * gg.z + bb.z;
    o.w = d3 * rstd * gg.w + bb.w;
    if (outF) *(float4*)(outF + row * kD + tid * 4) = o;
    if (outB) {
        bf16x4 ob;
        ob.x = (bf16)o.x; ob.y = (bf16)o.y; ob.z = (bf16)o.z; ob.w = (bf16)o.w;
        *(bf16x4*)(outB + row * kD + tid * 4) = ob;
    }
}

extern "C" void kernel_launch(void* const* d_in, const int* in_sizes, int n_in,
                              void* d_out, int out_size, void* d_ws, size_t ws_size,
                              hipStream_t stream) {
    const float* lags = (const float*)d_in[0];
    const float* W1   = (const float*)d_in[1];
    const float* b1   = (const float*)d_in[2];
    const float* W2   = (const float*)d_in[3];
    const float* b2   = (const float*)d_in[4];
    const float* g1   = (const float*)d_in[5];
    const float* be1  = (const float*)d_in[6];
    const float* g3   = (const float*)d_in[7];
    const float* be3  = (const float*)d_in[8];
    float* out = (float*)d_out;   // also used as fp32 scratch (x_pre, then y)

    // ---- workspace carve-up: 208 MiB total ----
    // lagsT  bf16 [16][1024][2048]   64 MiB   (V^T operand for PV)
    // lagsb  bf16 [16][2048][1024]   64 MiB   (QK^T operands; REUSED as xb after LN1)
    // W1T    bf16 [4096][1024]        8 MiB
    // W2T    bf16 [1024][4096]        8 MiB
    // SP     bf16                     64 MiB  (scores/probs [4][2048][2048]=32MiB,
    //                                          then h chunk [8192][4096]=64MiB)
    const size_t REQUIRED = (size_t)(64 + 64 + 8 + 8 + 64) * 1024 * 1024;
    if (ws_size < REQUIRED) return;   // clean-fail diagnostic instead of OOB crash

    char* w = (char*)d_ws;
    bf16* lagsT = (bf16*)w; w += (size_t)kB * kD * kS * 2;
    bf16* lagsb = (bf16*)w; w += (size_t)kB * kS * kD * 2;   // becomes xb
    bf16* W1T   = (bf16*)w; w += (size_t)kD * kE2 * 2;
    bf16* W2T   = (bf16*)w; w += (size_t)kE2 * kD * 2;
    bf16* SP    = (bf16*)w;                                  // scores/probs, then h
    bf16* xb    = lagsb;
    bf16* h     = SP;

    const int n = kB * kS * kD;

    // ---- operand prep ----
    cvt_bf16_kernel<<<n / 1024, 256, 0, stream>>>(lags, lagsb);
    transpose_cvt_kernel<<<dim3(kD / 32, kS / 32, kB), dim3(32, 8), 0, stream>>>(
        lags, lagsT, kS, kD, (long long)kS * kD, (long long)kD * kS);
    transpose_cvt_kernel<<<dim3(kE2 / 32, kD / 32, 1), dim3(32, 8), 0, stream>>>(
        W1, W1T, kD, kE2, 0, 0);
    transpose_cvt_kernel<<<dim3(kD / 32, kE2 / 32, 1), dim3(32, 8), 0, stream>>>(
        W2, W2T, kE2, kD, 0, 0);

    // ---- attention, kCB batches at a time ----
    for (int c = 0; c < kB / kCB; c++) {
        const size_t off = (size_t)c * kCB * kS * kD;   // same count for [b][s][d] and [b][d][s]
        // scores = bf16((lags @ lags^T) / 32)
        gemm_bt_kernel<0><<<dim3(kS / 128, kS / 128, kCB), 256, 0, stream>>>(
            lagsb + off, lagsb + off, nullptr, SP, nullptr, nullptr, nullptr,
            kS, kD, (long long)kS * kD, (long long)kS * kD, (long long)kS * kS, 0, 0.03125f);
        // P = softmax(scores), in place
        softmax_bf16_kernel<<<kCB * kS, 256, 0, stream>>>(SP);
        // x_pre = P @ V + lags   -> d_out (fp32)
        gemm_bt_kernel<1><<<dim3(kD / 128, kS / 128, kCB), 256, 0, stream>>>(
            SP, lagsT + off, out + off, nullptr, nullptr, lags + off, nullptr,
            kD, kS, (long long)kS * kS, (long long)kD * kS,
            (long long)kS * kD, (long long)kS * kD, 1.0f);
        // xb = bf16(LN1(x_pre))  (overwrites lagsb batches of this chunk)
        layernorm_kernel<<<kCB * kS, 256, 0, stream>>>(out + off, g1, be1, nullptr, xb + off);
    }

    // ---- FFN, kFR rows at a time (h aliases SP region) ----
    for (int c = 0; c < (kB * kS) / kFR; c++) {
        const size_t roff = (size_t)c * kFR * kD;
        // h = bf16(gelu(x @ W1 + b1))
        gemm_bt_kernel<2><<<dim3(kE2 / 128, kFR / 128, 1), 256, 0, stream>>>(
            xb + roff, W1T, nullptr, h, b1, nullptr, nullptr,
            kE2, kD, 0, 0, 0, 0, 1.0f);
        // y = h @ W2 + b2 + x    -> d_out (fp32)
        gemm_bt_kernel<3><<<dim3(kD / 128, kFR / 128, 1), 256, 0, stream>>>(
            h, W2T, out + roff, nullptr, b2, nullptr, xb + roff,
            kD, kE2, 0, 0, 0, 0, 1.0f);
    }

    // ---- out = LN2(y), in place ----
    layernorm_kernel<<<kB * kS, 256, 0, stream>>>(out, g3, be3, out, nullptr);
}